// Round 5
// baseline (216.799 us; speedup 1.0000x reference)
//
#include <hip/hip_runtime.h>
#include <math.h>

#define B_    2
#define NSEQ  8192
#define DIM_  512
#define H_    8
#define DH_   64
#define F_    256
#define M_    (B_*NSEQ)      // 16384
#define QKV_  1536

typedef __attribute__((ext_vector_type(8))) short     short8;
typedef __attribute__((ext_vector_type(4))) float     float4v;
typedef __attribute__((ext_vector_type(8))) unsigned short ushort8v;

__device__ __forceinline__ unsigned short f2bf(float f) {
    unsigned u = __float_as_uint(f);
    u += 0x7FFFu + ((u >> 16) & 1u);   // RNE
    return (unsigned short)(u >> 16);
}
__device__ __forceinline__ float bf2f(unsigned short h) {
    unsigned u = ((unsigned)h) << 16;
    return __uint_as_float(u);
}
// pack two floats -> two bf16 (truncate; bias cancels in N/D ratio)
__device__ __forceinline__ unsigned pack2bf(float lo, float hi) {
    return __builtin_amdgcn_perm(__float_as_uint(hi), __float_as_uint(lo), 0x07060302);
}
__device__ __forceinline__ void glds16(const void* g, void* s) {
    __builtin_amdgcn_global_load_lds(
        (const __attribute__((address_space(1))) unsigned int*)g,
        (__attribute__((address_space(3))) unsigned int*)s, 16, 0, 0);
}

// ---------------------------------------------------------------------------
// fused fp32->bf16 for all 4 inputs, one launch.
// ---------------------------------------------------------------------------
__global__ __launch_bounds__(256) void cvt_all(const float* __restrict__ x,
                                               const float* __restrict__ wqkv,
                                               const float* __restrict__ wout,
                                               const float* __restrict__ proj,
                                               unsigned short* __restrict__ xb,
                                               unsigned short* __restrict__ wqkvb,
                                               unsigned short* __restrict__ woutb,
                                               unsigned short* __restrict__ projb) {
    int bid = blockIdx.x;
    const float* in; unsigned short* out; int i;
    if (bid < 4096)      { in = x;    out = xb;    i = bid * 256 + threadIdx.x; }
    else if (bid < 4480) { in = wqkv; out = wqkvb; i = (bid - 4096) * 256 + threadIdx.x; }
    else if (bid < 4608) { in = wout; out = woutb; i = (bid - 4480) * 256 + threadIdx.x; }
    else                 { in = proj; out = projb; i = (bid - 4608) * 256 + threadIdx.x; }
    float4 a = ((const float4*)in)[2 * i];
    float4 b = ((const float4*)in)[2 * i + 1];
    ushort8v o;
    o[0] = f2bf(a.x); o[1] = f2bf(a.y); o[2] = f2bf(a.z); o[3] = f2bf(a.w);
    o[4] = f2bf(b.x); o[5] = f2bf(b.y); o[6] = f2bf(b.z); o[7] = f2bf(b.w);
    ((ushort8v*)out)[i] = o;
}

// ---------------------------------------------------------------------------
// gemm1: 128x128, 4 waves, 5-buffer ring (80 KB), prefetch DEPTH 4.
// Theory: per-step compute ~200-300cy/wave < 900cy HBM latency, so depth 2
// (rounds 1-3, all null) never covered it; depth 4 gives ~4 steps of cover.
// vmcnt ladder 12/8/4/0 = 4 loads/tile x tiles-in-flight-ahead.
// 2 blocks/CU (vs 3) — trades TLP for pipeline depth.
// vTout: V-columns (col>=1024) written transposed into vT.
// ---------------------------------------------------------------------------
template<bool BF16OUT>
__global__ __launch_bounds__(256) void gemm_nt_pp(const unsigned short* __restrict__ A,
                                                  const unsigned short* __restrict__ Bm,
                                                  const float* __restrict__ bias,
                                                  void* __restrict__ Cout,
                                                  unsigned short* __restrict__ vTout,
                                                  int M, int N, int K) {
    __shared__ __align__(16) unsigned short As[5][128 * 32];   // 40 KB
    __shared__ __align__(16) unsigned short Bs[5][128 * 32];   // 40 KB
    const int t  = threadIdx.x;
    const int w  = t >> 6, l = t & 63;
    const int wm = w >> 1, wn = w & 1;
    const int lr = l & 15, lq = l >> 4;

    // XCD-aware remap: contiguous tile range per XCD (flat % 8 = XCD)
    const int gx = gridDim.x;
    int flat = blockIdx.y * gx + blockIdx.x;
    int per  = (gx * gridDim.y) >> 3;
    int flat2 = (flat & 7) * per + (flat >> 3);
    const int m0 = (flat2 / gx) * 128, n0 = (flat2 % gx) * 128;

    float4v acc[4][4];
#pragma unroll
    for (int mi = 0; mi < 4; mi++)
#pragma unroll
        for (int ni = 0; ni < 4; ni++) acc[mi][ni] = (float4v){0.f, 0.f, 0.f, 0.f};

    // one BK=32 tile = 4 glds16 per thread (2 A + 2 B)
    auto stage = [&](int buf, int k0) {
#pragma unroll
        for (int i = 0; i < 2; i++) {
            int rb8 = w * 2 + i;
            int row = rb8 * 16 + lr;
            glds16(A + (size_t)(m0 + row) * K + k0 + lq * 8, &As[buf][rb8 * 512]);
            glds16(Bm + (size_t)(n0 + row) * K + k0 + lq * 8, &Bs[buf][rb8 * 512]);
        }
    };

    const int nk = K >> 5;          // 16 for K=512
    stage(0, 0);
    stage(1, 32);
    stage(2, 64);
    stage(3, 96);

    for (int k = 0; k < nk; k++) {
        // counted wait: tile k landed; up to 3 future tiles (12 loads) in flight
        if (k + 3 < nk)      { asm volatile("s_waitcnt vmcnt(12)" ::: "memory"); }
        else if (k + 2 < nk) { asm volatile("s_waitcnt vmcnt(8)"  ::: "memory"); }
        else if (k + 1 < nk) { asm volatile("s_waitcnt vmcnt(4)"  ::: "memory"); }
        else                 { asm volatile("s_waitcnt vmcnt(0)"  ::: "memory"); }
        __builtin_amdgcn_s_barrier();

        const int cur = k % 5;
        if (k + 4 < nk) stage((k + 4) % 5, (k + 4) << 5);

        short8 af[4], bfr[4];
#pragma unroll
        for (int mi = 0; mi < 4; mi++)
            af[mi] = *(const short8*)&As[cur][((wm * 4 + mi) * 64 + l) * 8];
#pragma unroll
        for (int ni = 0; ni < 4; ni++)
            bfr[ni] = *(const short8*)&Bs[cur][((wn * 4 + ni) * 64 + l) * 8];

        __builtin_amdgcn_s_setprio(1);
#pragma unroll
        for (int mi = 0; mi < 4; mi++)
#pragma unroll
            for (int ni = 0; ni < 4; ni++)
                acc[mi][ni] = __builtin_amdgcn_mfma_f32_16x16x32_bf16(
                    af[mi], bfr[ni], acc[mi][ni], 0, 0, 0);
        __builtin_amdgcn_s_setprio(0);
    }

    const int q = l >> 4, c = l & 15;      // C/D: col=lane&15, row=quad*4+reg
#pragma unroll
    for (int mi = 0; mi < 4; mi++) {
        int row0 = m0 + wm * 64 + mi * 16 + q * 4;
#pragma unroll
        for (int ni = 0; ni < 4; ni++) {
            int col = n0 + wn * 64 + ni * 16 + c;
            if (BF16OUT && vTout != nullptr && col >= 1024) {
                // V path: write transposed into vT[z=b*8+h][dh][seq]
                int cm = col - 1024;
                int h2 = cm >> 6, dh = cm & 63;
                int bq = row0 >> 13;
                size_t nn = (size_t)(row0 & 8191);
                unsigned short* dst = vTout + (((size_t)bq * 8 + h2) * 64 + dh) * NSEQ + nn;
                uint2 pv;
                pv.x = ((unsigned)f2bf(acc[mi][ni][1]) << 16) | f2bf(acc[mi][ni][0]);
                pv.y = ((unsigned)f2bf(acc[mi][ni][3]) << 16) | f2bf(acc[mi][ni][2]);
                *(uint2*)dst = pv;
            } else {
                float bv = bias ? bias[col] : 0.f;
#pragma unroll
                for (int r = 0; r < 4; r++) {
                    float v = acc[mi][ni][r] + bv;
                    if (BF16OUT) ((unsigned short*)Cout)[(size_t)(row0 + r) * N + col] = f2bf(v);
                    else         ((float*)Cout)[(size_t)(row0 + r) * N + col] = v;
                }
            }
        }
    }
}

// ---------------------------------------------------------------------------
// gemm2: round-1 form. BM=256, BN=128, BK=64, 512 threads, 3-ring, vmcnt(6).
// fp32 out + bias. K hardcoded 512 (nk=8). Unchanged from round 4.
// ---------------------------------------------------------------------------
__global__ __launch_bounds__(512) void gemm_out_256(const unsigned short* __restrict__ A,
                                                    const unsigned short* __restrict__ Bm,
                                                    const float* __restrict__ bias,
                                                    float* __restrict__ Cout,
                                                    int M, int N, int K) {
    __shared__ __align__(16) unsigned short As[3][32 * 512];   // 96 KB
    __shared__ __align__(16) unsigned short Bs[3][16 * 512];   // 48 KB
    const int t  = threadIdx.x;
    const int w  = t >> 6, l = t & 63;
    const int wm = w >> 1, wn = w & 1;
    const int lr = l & 15, lq = l >> 4;

    const int gx = gridDim.x;
    int flat = blockIdx.y * gx + blockIdx.x;
    int per  = (gx * gridDim.y) >> 3;
    int flat2 = (flat & 7) * per + (flat >> 3);
    const int m0 = (flat2 / gx) * 256, n0 = (flat2 % gx) * 128;

    float4v acc[4][4];
#pragma unroll
    for (int mi = 0; mi < 4; mi++)
#pragma unroll
        for (int ni = 0; ni < 4; ni++) acc[mi][ni] = (float4v){0.f, 0.f, 0.f, 0.f};

    auto stage = [&](int buf, int k0) {
#pragma unroll
        for (int i = 0; i < 4; i++) {
            int c = w * 4 + i, rb = c >> 1, ks = c & 1;
            glds16(A + (size_t)(m0 + rb * 16 + lr) * K + k0 + ks * 32 + lq * 8,
                   &As[buf][c * 512]);
        }
#pragma unroll
        for (int i = 0; i < 2; i++) {
            int c = w * 2 + i, rb = c >> 1, ks = c & 1;
            glds16(Bm + (size_t)(n0 + rb * 16 + lr) * K + k0 + ks * 32 + lq * 8,
                   &Bs[buf][c * 512]);
        }
    };

    stage(0, 0);
    stage(1, 64);

#pragma unroll
    for (int k = 0; k < 8; k++) {
        if (k < 7) { asm volatile("s_waitcnt vmcnt(6)" ::: "memory"); }
        else       { asm volatile("s_waitcnt vmcnt(0)" ::: "memory"); }
        __builtin_amdgcn_s_barrier();
        const int cur = k % 3;

        if (k + 2 < 8) stage((k + 2) % 3, (k + 2) << 6);

        short8 af[2][4], bfr[2][4];
#pragma unroll
        for (int ks = 0; ks < 2; ks++) {
#pragma unroll
            for (int mi = 0; mi < 4; mi++)
                af[ks][mi] = *(const short8*)&As[cur][(((wm * 4 + mi) * 2 + ks) * 64 + l) * 8];
#pragma unroll
            for (int ni = 0; ni < 4; ni++)
                bfr[ks][ni] = *(const short8*)&Bs[cur][(((wn * 4 + ni) * 2 + ks) * 64 + l) * 8];
        }

        __builtin_amdgcn_s_setprio(1);
#pragma unroll
        for (int ks = 0; ks < 2; ks++)
#pragma unroll
            for (int mi = 0; mi < 4; mi++)
#pragma unroll
                for (int ni = 0; ni < 4; ni++)
                    acc[mi][ni] = __builtin_amdgcn_mfma_f32_16x16x32_bf16(
                        af[ks][mi], bfr[ks][ni], acc[mi][ni], 0, 0, 0);
        __builtin_amdgcn_s_setprio(0);
    }

    const int q = l >> 4, c = l & 15;
#pragma unroll
    for (int mi = 0; mi < 4; mi++) {
        int row0 = m0 + wm * 64 + mi * 16 + q * 4;
#pragma unroll
        for (int ni = 0; ni < 4; ni++) {
            int col = n0 + wn * 64 + ni * 16 + c;
            float bv = bias ? bias[col] : 0.f;
#pragma unroll
            for (int r = 0; r < 4; r++)
                Cout[(size_t)(row0 + r) * N + col] = acc[mi][ni][r] + bv;
        }
    }
}

// ---------------------------------------------------------------------------
// Fused k' featuremap + split-K context. NEW: KB/VB double-buffered with
// glds prefetch of step st+1 issued at the START of step st's compute —
// the ~1000-1500cy compute phase (36 MFMA + 32 exp + repack) fully hides
// the ~900cy load latency (T14 regime). ONE barrier per step (was 2 +
// full vmcnt(0) drain). LDS 64 KB -> 2 blocks/CU = grid/CU (no occ loss).
// KPA is wave-local (verified: no barrier between exp-write and phase B).
// ---------------------------------------------------------------------------
__global__ __launch_bounds__(256) void ctx_fused_mfma(
    const unsigned short* __restrict__ qkvb,
    const unsigned short* __restrict__ projb,
    const unsigned short* __restrict__ vT,
    unsigned short* __restrict__ partial)   // [16 s][16 z][80][256] bf16
{
    __shared__ __align__(16) unsigned short PB[16 * 512];      // 16 KB, resident
    __shared__ __align__(16) unsigned short KB[2][8 * 512];    // 16 KB dbuf
    __shared__ __align__(16) unsigned short VB[2][8 * 512];    // 16 KB dbuf
    __shared__ __align__(16) unsigned short KPA[16 * 512];     // 16 KB, wave-local
    const int t = threadIdx.x, w = t >> 6, l = t & 63;
    const int lr = l & 15, lq = l >> 4;
    const int s = blockIdx.x, fh = blockIdx.y, z = blockIdx.z;
    const int b = z >> 3, h = z & 7;
    const int nchunk = s * 512;

    auto stageKV = [&](int bi, int nbase) {
        for (int idx = w; idx < 8; idx += 4) {
            int nblk = idx >> 1, kt = idx & 1;
            glds16(qkvb + ((size_t)b * NSEQ + nbase + nblk * 16 + lr) * QKV_ + 512 + h * 64 + kt * 32 + lq * 8,
                   &KB[bi][idx * 512]);
        }
        for (int idx = w; idx < 8; idx += 4) {
            int dhb = idx >> 1, nt2 = idx & 1;
            glds16(vT + ((size_t)z * 64 + dhb * 16 + lr) * NSEQ + nbase + nt2 * 32 + lq * 8,
                   &VB[bi][idx * 512]);
        }
    };

    // prologue: PB (4 glds/thread) + step-0 K/V (4 glds/thread)
    for (int idx = w; idx < 16; idx += 4) {
        int fblk = idx >> 1, kt = idx & 1;
        glds16(projb + (size_t)(fh * 128 + fblk * 16 + lr) * 64 + kt * 32 + lq * 8, &PB[idx * 512]);
    }
    stageKV(0, nchunk);

    float4v acc[2][5];
#pragma unroll
    for (int mi = 0; mi < 2; mi++)
#pragma unroll
        for (int ni = 0; ni < 5; ni++) acc[mi][ni] = (float4v){0.f, 0.f, 0.f, 0.f};
    short ov = (lr == 0) ? (short)0x3F80 : (short)0;
    short8 ones = {ov, ov, ov, ov, ov, ov, ov, ov};

    for (int st = 0; st < 8; st++) {
        // loads for buf[cur] were issued one full compute-phase ago -> drain is ~free
        asm volatile("s_waitcnt vmcnt(0)" ::: "memory");
        __builtin_amdgcn_s_barrier();       // all waves' loads landed; prev reads of buf^1 done
        asm volatile("" ::: "memory");
        const int cur = st & 1;
        if (st < 7) stageKV(cur ^ 1, nchunk + (st + 1) * 64);

        // phase A: rows n (mi 0..3), cols f' (wave w: 32 f, ni 0..1)
        float4v a2[4][2];
#pragma unroll
        for (int mi = 0; mi < 4; mi++)
#pragma unroll
            for (int ni = 0; ni < 2; ni++) a2[mi][ni] = (float4v){0.f, 0.f, 0.f, 0.f};
#pragma unroll
        for (int ks = 0; ks < 2; ks++) {
            short8 ka[4], pb[2];
#pragma unroll
            for (int mi = 0; mi < 4; mi++)
                ka[mi] = *(const short8*)&KB[cur][((mi * 2 + ks) * 64 + l) * 8];
#pragma unroll
            for (int ni = 0; ni < 2; ni++)
                pb[ni] = *(const short8*)&PB[(((w * 2 + ni) * 2 + ks) * 64 + l) * 8];
#pragma unroll
            for (int mi = 0; mi < 4; mi++)
#pragma unroll
                for (int ni = 0; ni < 2; ni++)
                    a2[mi][ni] = __builtin_amdgcn_mfma_f32_16x16x32_bf16(ka[mi], pb[ni], a2[mi][ni], 0, 0, 0);
        }
        // exp -> bf16 -> KPA (A-frag order, wave-local rows)
#pragma unroll
        for (int mi = 0; mi < 4; mi++) {
            int nb = mi * 16 + lq * 4;
            int qoff = ((nb >> 3) & 3) * 256 + (nb & 7) * 2;
            int setn = nb >> 5;
#pragma unroll
            for (int ni = 0; ni < 2; ni++) {
                int fp = w * 32 + ni * 16 + lr;
                float e0 = __expf(a2[mi][ni][0]);
                float e1 = __expf(a2[mi][ni][1]);
                float e2 = __expf(a2[mi][ni][2]);
                float e3 = __expf(a2[mi][ni][3]);
                uint2 p; p.x = pack2bf(e0, e1); p.y = pack2bf(e2, e3);
                *(uint2*)((char*)KPA + (size_t)(((fp >> 4) * 2 + setn) * 1024 + qoff + (fp & 15) * 16)) = p;
            }
        }
        // phase B: rows f' (wave w: mi 0..1), cols dh_ext (ni; ni=4 -> ksum)
#pragma unroll
        for (int ks = 0; ks < 2; ks++) {
            short8 af[2], bf[4];
#pragma unroll
            for (int mi = 0; mi < 2; mi++)
                af[mi] = *(const short8*)&KPA[(((w * 2 + mi) * 2 + ks) * 64 + l) * 8];
#pragma unroll
            for (int ni = 0; ni < 4; ni++)
                bf[ni] = *(const short8*)&VB[cur][((ni * 2 + ks) * 64 + l) * 8];
#pragma unroll
            for (int mi = 0; mi < 2; mi++) {
#pragma unroll
                for (int ni = 0; ni < 4; ni++)
                    acc[mi][ni] = __builtin_amdgcn_mfma_f32_16x16x32_bf16(af[mi], bf[ni], acc[mi][ni], 0, 0, 0);
                acc[mi][4] = __builtin_amdgcn_mfma_f32_16x16x32_bf16(af[mi], ones, acc[mi][4], 0, 0, 0);
            }
        }
    }
    unsigned short* base = partial + (size_t)(s * 16 + z) * 80 * 256 + fh * 128;
#pragma unroll
    for (int mi = 0; mi < 2; mi++) {
        int f0r = w * 32 + mi * 16 + lq * 4;
#pragma unroll
        for (int ni = 0; ni < 5; ni++) {
            int col = ni * 16 + lr;
#pragma unroll
            for (int r = 0; r < 4; r++)
                base[(size_t)col * 256 + f0r + r] = f2bf(acc[mi][ni][r]);
        }
    }
}

// ---------------------------------------------------------------------------
// Reduce split-K bf16 partials (16 splits) -> ctxT bf16 [z][80][256].
// 640 blocks (2.5/CU), 2 bf16 per thread.
// ---------------------------------------------------------------------------
__global__ __launch_bounds__(256) void ctx_reduce(const unsigned short* __restrict__ partial,
                                                  unsigned short* __restrict__ ctxT) {
    int idx2 = blockIdx.x * 256 + threadIdx.x;   // 0 .. 163839
    const int INNER = 16 * 80 * 256;
    size_t off = (size_t)idx2 * 2;
    float s0 = 0.f, s1 = 0.f;
#pragma unroll
    for (int k = 0; k < 16; k++) {
        unsigned v = *(const unsigned*)(partial + (size_t)k * INNER + off);
        s0 += bf2f((unsigned short)(v & 0xffffu));
        s1 += bf2f((unsigned short)(v >> 16));
    }
    *(unsigned*)(ctxT + off) = ((unsigned)f2bf(s1) << 16) | f2bf(s0);
}

// ---------------------------------------------------------------------------
// Fused q' featuremap + (q'.ctx_ext). NEW: PA/CB double-buffered with
// prefetch under the long compute phase (same T14 structure as ctx_fused).
// One barrier per fs-step. LDS 68 KB -> 2 blocks/CU. QPA wave-local.
// ---------------------------------------------------------------------------
__global__ __launch_bounds__(256) void attn_fused_mfma(
    const unsigned short* __restrict__ qkvb,
    const unsigned short* __restrict__ projb,
    const unsigned short* __restrict__ ctxT,
    unsigned short* __restrict__ attnb)
{
    __shared__ __align__(16) unsigned short QB[16 * 512];      // 16 KB, resident
    __shared__ __align__(16) unsigned short PA[2][8 * 512];    // 16 KB dbuf
    __shared__ __align__(16) unsigned short QPA[16 * 512];     // 16 KB, wave-local
    __shared__ __align__(16) unsigned short CB[2][10 * 512];   // 20 KB dbuf
    const int t = threadIdx.x, w = t >> 6, l = t & 63;
    const int lr = l & 15, lq = l >> 4;
    const int m0 = blockIdx.x * 128, z = blockIdx.y;
    const int b = z >> 3, h = z & 7;

    auto stagePC = [&](int bi, int f0n) {
        for (int idx = w; idx < 8; idx += 4) {
            int fb = idx >> 1, kt = idx & 1;
            glds16(projb + (size_t)(f0n + fb * 16 + lr) * 64 + kt * 32 + lq * 8, &PA[bi][idx * 512]);
        }
        for (int idx = w; idx < 10; idx += 4) {
            int dhb = idx >> 1, ft = idx & 1;
            glds16(ctxT + ((size_t)z * 80 + dhb * 16 + lr) * 256 + f0n + ft * 32 + lq * 8,
                   &CB[bi][idx * 512]);
        }
    };

    // prologue: QB (4/thread) + step-0 PA/CB
    for (int idx = w; idx < 16; idx += 4) {
        int mblk = idx >> 1, kt = idx & 1;
        glds16(qkvb + ((size_t)b * NSEQ + m0 + mblk * 16 + lr) * QKV_ + h * 64 + kt * 32 + lq * 8,
               &QB[idx * 512]);
    }
    stagePC(0, 0);

    float4v acc[2][5];
#pragma unroll
    for (int mi = 0; mi < 2; mi++)
#pragma unroll
        for (int ni = 0; ni < 5; ni++) acc[mi][ni] = (float4v){0.f, 0.f, 0.f, 0.f};

    for (int fs = 0; fs < 4; fs++) {
        asm volatile("s_waitcnt vmcnt(0)" ::: "memory");
        __builtin_amdgcn_s_barrier();
        asm volatile("" ::: "memory");
        const int cur = fs & 1;
        if (fs < 3) stagePC(cur ^ 1, (fs + 1) * 64);

        float4v a2[4][2];
#pragma unroll
        for (int mi = 0; mi < 4; mi++)
#pragma unroll
            for (int ni = 0; ni < 2; ni++) a2[mi][ni] = (float4v){0.f, 0.f, 0.f, 0.f};
#pragma unroll
        for (int ks = 0; ks < 2; ks++) {
            short8 pa[4], qb[2];
#pragma unroll
            for (int mi = 0; mi < 4; mi++)
                pa[mi] = *(const short8*)&PA[cur][((mi * 2 + ks) * 64 + l) * 8];
#pragma unroll
            for (int ni = 0; ni < 2; ni++)
                qb[ni] = *(const short8*)&QB[(((w * 2 + ni) * 2 + ks) * 64 + l) * 8];
#pragma unroll
            for (int mi = 0; mi < 4; mi++)
#pragma unroll
                for (int ni = 0; ni < 2; ni++)
                    a2[mi][ni] = __builtin_amdgcn_mfma_f32_16x16x32_bf16(pa[mi], qb[ni], a2[mi][ni], 0, 0, 0);
        }
#pragma unroll
        for (int mi = 0; mi < 4; mi++) {
            int fb2 = mi * 16 + lq * 4;
            int qoff = ((fb2 >> 3) & 3) * 256 + (fb2 & 7) * 2;
            int setf = fb2 >> 5;
#pragma unroll
            for (int ni = 0; ni < 2; ni++) {
                int m = w * 32 + ni * 16 + lr;
                float e0 = __expf(0.125f * a2[mi][ni][0]);
                float e1 = __expf(0.125f * a2[mi][ni][1]);
                float e2 = __expf(0.125f * a2[mi][ni][2]);
                float e3 = __expf(0.125f * a2[mi][ni][3]);
                uint2 p; p.x = pack2bf(e0, e1); p.y = pack2bf(e2, e3);
                *(uint2*)((char*)QPA + (size_t)(((m >> 4) * 2 + setf) * 1024 + qoff + (m & 15) * 16)) = p;
            }
        }
#pragma unroll
        for (int ks = 0; ks < 2; ks++) {
            short8 af[2], cb[5];
#pragma unroll
            for (int mi = 0; mi < 2; mi++)
                af[mi] = *(const short8*)&QPA[(((w * 2 + mi) * 2 + ks) * 64 + l) * 8];
#pragma unroll
            for (int ni = 0; ni < 5; ni++)
                cb[ni] = *(const short8*)&CB[cur][((ni * 2 + ks) * 64 + l) * 8];
#pragma unroll
            for (int mi = 0; mi < 2; mi++)
#pragma unroll
                for (int ni = 0; ni < 5; ni++)
                    acc[mi][ni] = __builtin_amdgcn_mfma_f32_16x16x32_bf16(af[mi], cb[ni], acc[mi][ni], 0, 0, 0);
        }
    }
#pragma unroll
    for (int mi = 0; mi < 2; mi++) {
        int rowb = m0 + w * 32 + mi * 16 + lq * 4;
#pragma unroll
        for (int r = 0; r < 4; r++) {
            float dv = __shfl(acc[mi][4][r], (l & 48), 64);
            float rinv = 1.f / (dv + 1e-6f);
#pragma unroll
            for (int ni = 0; ni < 4; ni++)
                attnb[((size_t)b * NSEQ + rowb + r) * 512 + h * 64 + ni * 16 + lr] =
                    f2bf(acc[mi][ni][r] * rinv);
        }
    }
}

// ---------------------------------------------------------------------------
extern "C" void kernel_launch(void* const* d_in, const int* in_sizes, int n_in,
                              void* d_out, int out_size, void* d_ws, size_t ws_size,
                              hipStream_t stream) {
    const float* x    = (const float*)d_in[0];
    const float* Wqkv = (const float*)d_in[1];
    const float* Wout = (const float*)d_in[2];
    const float* bout = (const float*)d_in[3];
    const float* proj = (const float*)d_in[4];

    unsigned short* qkvb    = (unsigned short*)d_ws;                 // 25,165,824 u16
    unsigned short* vT      = qkvb + (size_t)M_ * QKV_;              // 8,388,608 u16
    unsigned short* partial = vT + (size_t)16 * 64 * NSEQ;           // 5,242,880 u16 (bf16, 16 splits)
    unsigned short* ctxT    = partial + (size_t)16 * 16 * 80 * 256;  // 327,680 u16
    unsigned short* projb   = ctxT + (size_t)16 * 80 * 256;          // 16,384 u16
    unsigned short* xb      = projb + 16384;                         // 8,388,608 u16
    unsigned short* attnb   = xb;                                    // overlay (xb dead after gemm1)
    unsigned short* wqkvb   = xb + (size_t)M_ * DIM_;                // 786,432 u16
    unsigned short* woutb   = wqkvb + (size_t)QKV_ * DIM_;           // 262,144 u16
    float* outp = (float*)d_out;                                     // total ws ~97 MB

    // 0) fp32 -> bf16 (single launch)
    cvt_all<<<dim3(4616), 256, 0, stream>>>(x, Wqkv, Wout, proj, xb, wqkvb, woutb, projb);
    // 1) qkv = x @ Wqkv^T — depth-4 ring; grid (12, 128) = 1536 blocks (%8==0)
    gemm_nt_pp<true><<<dim3(QKV_ / 128, M_ / 128), 256, 0, stream>>>(xb, wqkvb, nullptr, qkvb, vT, M_, QKV_, DIM_);
    // 2) fused k' + context partials — dbuf prefetch, 1 barrier/step
    ctx_fused_mfma<<<dim3(16, 2, 16), 256, 0, stream>>>(qkvb, projb, vT, partial);
    // 3) reduce -> ctxT bf16 (incl. ksum row)
    ctx_reduce<<<dim3(640), 256, 0, stream>>>(partial, ctxT);
    // 4) fused q' + attention out — dbuf prefetch, 1 barrier/step
    attn_fused_mfma<<<dim3(64, 16), 256, 0, stream>>>(qkvb, projb, ctxT, attnb);
    // 5) out = attn @ Wout^T + bout — grid (4, 64) = 256 blocks
    gemm_out_256<<<dim3(DIM_ / 128, M_ / 256), 512, 0, stream>>>(attnb, woutb, bout, outp, M_, DIM_, DIM_);
}

// Round 6
// 210.165 us; speedup vs baseline: 1.0316x; 1.0316x over previous
//
#include <hip/hip_runtime.h>
#include <math.h>

#define B_    2
#define NSEQ  8192
#define DIM_  512
#define H_    8
#define DH_   64
#define F_    256
#define M_    (B_*NSEQ)      // 16384
#define QKV_  1536

typedef __attribute__((ext_vector_type(8))) short     short8;
typedef __attribute__((ext_vector_type(4))) float     float4v;
typedef __attribute__((ext_vector_type(8))) unsigned short ushort8v;

__device__ __forceinline__ unsigned short f2bf(float f) {
    unsigned u = __float_as_uint(f);
    u += 0x7FFFu + ((u >> 16) & 1u);   // RNE
    return (unsigned short)(u >> 16);
}
__device__ __forceinline__ float bf2f(unsigned short h) {
    unsigned u = ((unsigned)h) << 16;
    return __uint_as_float(u);
}
// pack two floats -> two bf16 (truncate; bias cancels in N/D ratio)
__device__ __forceinline__ unsigned pack2bf(float lo, float hi) {
    return __builtin_amdgcn_perm(__float_as_uint(hi), __float_as_uint(lo), 0x07060302);
}
__device__ __forceinline__ void glds16(const void* g, void* s) {
    __builtin_amdgcn_global_load_lds(
        (const __attribute__((address_space(1))) unsigned int*)g,
        (__attribute__((address_space(3))) unsigned int*)s, 16, 0, 0);
}

// ---------------------------------------------------------------------------
// fused fp32->bf16 for all 4 inputs, one launch.
// ---------------------------------------------------------------------------
__global__ __launch_bounds__(256) void cvt_all(const float* __restrict__ x,
                                               const float* __restrict__ wqkv,
                                               const float* __restrict__ wout,
                                               const float* __restrict__ proj,
                                               unsigned short* __restrict__ xb,
                                               unsigned short* __restrict__ wqkvb,
                                               unsigned short* __restrict__ woutb,
                                               unsigned short* __restrict__ projb) {
    int bid = blockIdx.x;
    const float* in; unsigned short* out; int i;
    if (bid < 4096)      { in = x;    out = xb;    i = bid * 256 + threadIdx.x; }
    else if (bid < 4480) { in = wqkv; out = wqkvb; i = (bid - 4096) * 256 + threadIdx.x; }
    else if (bid < 4608) { in = wout; out = woutb; i = (bid - 4480) * 256 + threadIdx.x; }
    else                 { in = proj; out = projb; i = (bid - 4608) * 256 + threadIdx.x; }
    float4 a = ((const float4*)in)[2 * i];
    float4 b = ((const float4*)in)[2 * i + 1];
    ushort8v o;
    o[0] = f2bf(a.x); o[1] = f2bf(a.y); o[2] = f2bf(a.z); o[3] = f2bf(a.w);
    o[4] = f2bf(b.x); o[5] = f2bf(b.y); o[6] = f2bf(b.z); o[7] = f2bf(b.w);
    ((ushort8v*)out)[i] = o;
}

// ---------------------------------------------------------------------------
// gemm1: BEST MEASURED (63.3-65.0 us, rounds 3/4). 128x128, 4 waves,
// 3-buffer ring (48 KB), counted vmcnt(4), 3 blocks/CU. FROZEN — depth-4
// (r5: 72.5us), coarse 256-tile (r1: 71.5), fine-phase (r2: 73.0) all worse.
// vTout: V-columns (col>=1024) written transposed into vT.
// ---------------------------------------------------------------------------
template<bool BF16OUT>
__global__ __launch_bounds__(256) void gemm_nt_pp(const unsigned short* __restrict__ A,
                                                  const unsigned short* __restrict__ Bm,
                                                  const float* __restrict__ bias,
                                                  void* __restrict__ Cout,
                                                  unsigned short* __restrict__ vTout,
                                                  int M, int N, int K) {
    __shared__ __align__(16) unsigned short As[3][128 * 32];
    __shared__ __align__(16) unsigned short Bs[3][128 * 32];
    const int t  = threadIdx.x;
    const int w  = t >> 6, l = t & 63;
    const int wm = w >> 1, wn = w & 1;
    const int lr = l & 15, lq = l >> 4;

    // XCD-aware remap: contiguous tile range per XCD (flat % 8 = XCD)
    const int gx = gridDim.x;
    int flat = blockIdx.y * gx + blockIdx.x;
    int per  = (gx * gridDim.y) >> 3;
    int flat2 = (flat & 7) * per + (flat >> 3);
    const int m0 = (flat2 / gx) * 128, n0 = (flat2 % gx) * 128;

    float4v acc[4][4];
#pragma unroll
    for (int mi = 0; mi < 4; mi++)
#pragma unroll
        for (int ni = 0; ni < 4; ni++) acc[mi][ni] = (float4v){0.f, 0.f, 0.f, 0.f};

    // one BK=32 tile = 4 glds16 per thread (2 A + 2 B)
    auto stage = [&](int buf, int k0) {
#pragma unroll
        for (int i = 0; i < 2; i++) {
            int rb8 = w * 2 + i;
            int row = rb8 * 16 + lr;
            glds16(A + (size_t)(m0 + row) * K + k0 + lq * 8, &As[buf][rb8 * 512]);
            glds16(Bm + (size_t)(n0 + row) * K + k0 + lq * 8, &Bs[buf][rb8 * 512]);
        }
    };

    const int nk = K >> 5;          // 16 for K=512
    stage(0, 0);
    stage(1, 32);

    for (int k = 0; k < nk; k++) {
        // counted wait: tile k landed; tile k+1's 4 loads stay in flight
        if (k + 1 < nk) { asm volatile("s_waitcnt vmcnt(4)" ::: "memory"); }
        else            { asm volatile("s_waitcnt vmcnt(0)" ::: "memory"); }
        __builtin_amdgcn_s_barrier();

        const int cur = k % 3;
        if (k + 2 < nk) stage((k + 2) % 3, (k + 2) << 5);

        short8 af[4], bfr[4];
#pragma unroll
        for (int mi = 0; mi < 4; mi++)
            af[mi] = *(const short8*)&As[cur][((wm * 4 + mi) * 64 + l) * 8];
#pragma unroll
        for (int ni = 0; ni < 4; ni++)
            bfr[ni] = *(const short8*)&Bs[cur][((wn * 4 + ni) * 64 + l) * 8];

        __builtin_amdgcn_s_setprio(1);
#pragma unroll
        for (int mi = 0; mi < 4; mi++)
#pragma unroll
            for (int ni = 0; ni < 4; ni++)
                acc[mi][ni] = __builtin_amdgcn_mfma_f32_16x16x32_bf16(
                    af[mi], bfr[ni], acc[mi][ni], 0, 0, 0);
        __builtin_amdgcn_s_setprio(0);
    }

    const int q = l >> 4, c = l & 15;      // C/D: col=lane&15, row=quad*4+reg
#pragma unroll
    for (int mi = 0; mi < 4; mi++) {
        int row0 = m0 + wm * 64 + mi * 16 + q * 4;
#pragma unroll
        for (int ni = 0; ni < 4; ni++) {
            int col = n0 + wn * 64 + ni * 16 + c;
            if (BF16OUT && vTout != nullptr && col >= 1024) {
                // V path: write transposed into vT[z=b*8+h][dh][seq]
                int cm = col - 1024;
                int h2 = cm >> 6, dh = cm & 63;
                int bq = row0 >> 13;
                size_t nn = (size_t)(row0 & 8191);
                unsigned short* dst = vTout + (((size_t)bq * 8 + h2) * 64 + dh) * NSEQ + nn;
                uint2 pv;
                pv.x = ((unsigned)f2bf(acc[mi][ni][1]) << 16) | f2bf(acc[mi][ni][0]);
                pv.y = ((unsigned)f2bf(acc[mi][ni][3]) << 16) | f2bf(acc[mi][ni][2]);
                *(uint2*)dst = pv;
            } else {
                float bv = bias ? bias[col] : 0.f;
#pragma unroll
                for (int r = 0; r < 4; r++) {
                    float v = acc[mi][ni][r] + bv;
                    if (BF16OUT) ((unsigned short*)Cout)[(size_t)(row0 + r) * N + col] = f2bf(v);
                    else         ((float*)Cout)[(size_t)(row0 + r) * N + col] = v;
                }
            }
        }
    }
}

// ---------------------------------------------------------------------------
// gemm2: round-1/4 form. BM=256, BN=128, BK=64, 512 threads, 3-ring, vmcnt(6).
// fp32 out + bias. K hardcoded 512 (nk=8).
// ---------------------------------------------------------------------------
__global__ __launch_bounds__(512) void gemm_out_256(const unsigned short* __restrict__ A,
                                                    const unsigned short* __restrict__ Bm,
                                                    const float* __restrict__ bias,
                                                    float* __restrict__ Cout,
                                                    int M, int N, int K) {
    __shared__ __align__(16) unsigned short As[3][32 * 512];   // 96 KB
    __shared__ __align__(16) unsigned short Bs[3][16 * 512];   // 48 KB
    const int t  = threadIdx.x;
    const int w  = t >> 6, l = t & 63;
    const int wm = w >> 1, wn = w & 1;
    const int lr = l & 15, lq = l >> 4;

    const int gx = gridDim.x;
    int flat = blockIdx.y * gx + blockIdx.x;
    int per  = (gx * gridDim.y) >> 3;
    int flat2 = (flat & 7) * per + (flat >> 3);
    const int m0 = (flat2 / gx) * 256, n0 = (flat2 % gx) * 128;

    float4v acc[4][4];
#pragma unroll
    for (int mi = 0; mi < 4; mi++)
#pragma unroll
        for (int ni = 0; ni < 4; ni++) acc[mi][ni] = (float4v){0.f, 0.f, 0.f, 0.f};

    auto stage = [&](int buf, int k0) {
#pragma unroll
        for (int i = 0; i < 4; i++) {
            int c = w * 4 + i, rb = c >> 1, ks = c & 1;
            glds16(A + (size_t)(m0 + rb * 16 + lr) * K + k0 + ks * 32 + lq * 8,
                   &As[buf][c * 512]);
        }
#pragma unroll
        for (int i = 0; i < 2; i++) {
            int c = w * 2 + i, rb = c >> 1, ks = c & 1;
            glds16(Bm + (size_t)(n0 + rb * 16 + lr) * K + k0 + ks * 32 + lq * 8,
                   &Bs[buf][c * 512]);
        }
    };

    stage(0, 0);
    stage(1, 64);

#pragma unroll
    for (int k = 0; k < 8; k++) {
        if (k < 7) { asm volatile("s_waitcnt vmcnt(6)" ::: "memory"); }
        else       { asm volatile("s_waitcnt vmcnt(0)" ::: "memory"); }
        __builtin_amdgcn_s_barrier();
        const int cur = k % 3;

        if (k + 2 < 8) stage((k + 2) % 3, (k + 2) << 6);

        short8 af[2][4], bfr[2][4];
#pragma unroll
        for (int ks = 0; ks < 2; ks++) {
#pragma unroll
            for (int mi = 0; mi < 4; mi++)
                af[ks][mi] = *(const short8*)&As[cur][(((wm * 4 + mi) * 2 + ks) * 64 + l) * 8];
#pragma unroll
            for (int ni = 0; ni < 4; ni++)
                bfr[ks][ni] = *(const short8*)&Bs[cur][(((wn * 4 + ni) * 2 + ks) * 64 + l) * 8];
        }

        __builtin_amdgcn_s_setprio(1);
#pragma unroll
        for (int ks = 0; ks < 2; ks++)
#pragma unroll
            for (int mi = 0; mi < 4; mi++)
#pragma unroll
                for (int ni = 0; ni < 4; ni++)
                    acc[mi][ni] = __builtin_amdgcn_mfma_f32_16x16x32_bf16(
                        af[ks][mi], bfr[ks][ni], acc[mi][ni], 0, 0, 0);
        __builtin_amdgcn_s_setprio(0);
    }

    const int q = l >> 4, c = l & 15;
#pragma unroll
    for (int mi = 0; mi < 4; mi++) {
        int row0 = m0 + wm * 64 + mi * 16 + q * 4;
#pragma unroll
        for (int ni = 0; ni < 4; ni++) {
            int col = n0 + wn * 64 + ni * 16 + c;
            float bv = bias ? bias[col] : 0.f;
#pragma unroll
            for (int r = 0; r < 4; r++)
                Cout[(size_t)(row0 + r) * N + col] = acc[mi][ni][r] + bv;
        }
    }
}

// ---------------------------------------------------------------------------
// Fused k' featuremap + split-K context. Round-5 dbuf form (measured −3.6us
// vs 2-barrier): KB/VB double-buffered, prefetch of st+1 at start of st's
// compute; ONE barrier per step. LDS 64 KB -> 2 blocks/CU.
// ---------------------------------------------------------------------------
__global__ __launch_bounds__(256) void ctx_fused_mfma(
    const unsigned short* __restrict__ qkvb,
    const unsigned short* __restrict__ projb,
    const unsigned short* __restrict__ vT,
    unsigned short* __restrict__ partial)   // [16 s][16 z][80][256] bf16
{
    __shared__ __align__(16) unsigned short PB[16 * 512];      // 16 KB, resident
    __shared__ __align__(16) unsigned short KB[2][8 * 512];    // 16 KB dbuf
    __shared__ __align__(16) unsigned short VB[2][8 * 512];    // 16 KB dbuf
    __shared__ __align__(16) unsigned short KPA[16 * 512];     // 16 KB, wave-local
    const int t = threadIdx.x, w = t >> 6, l = t & 63;
    const int lr = l & 15, lq = l >> 4;
    const int s = blockIdx.x, fh = blockIdx.y, z = blockIdx.z;
    const int b = z >> 3, h = z & 7;
    const int nchunk = s * 512;

    auto stageKV = [&](int bi, int nbase) {
        for (int idx = w; idx < 8; idx += 4) {
            int nblk = idx >> 1, kt = idx & 1;
            glds16(qkvb + ((size_t)b * NSEQ + nbase + nblk * 16 + lr) * QKV_ + 512 + h * 64 + kt * 32 + lq * 8,
                   &KB[bi][idx * 512]);
        }
        for (int idx = w; idx < 8; idx += 4) {
            int dhb = idx >> 1, nt2 = idx & 1;
            glds16(vT + ((size_t)z * 64 + dhb * 16 + lr) * NSEQ + nbase + nt2 * 32 + lq * 8,
                   &VB[bi][idx * 512]);
        }
    };

    // prologue: PB (4 glds/thread) + step-0 K/V (4 glds/thread)
    for (int idx = w; idx < 16; idx += 4) {
        int fblk = idx >> 1, kt = idx & 1;
        glds16(projb + (size_t)(fh * 128 + fblk * 16 + lr) * 64 + kt * 32 + lq * 8, &PB[idx * 512]);
    }
    stageKV(0, nchunk);

    float4v acc[2][5];
#pragma unroll
    for (int mi = 0; mi < 2; mi++)
#pragma unroll
        for (int ni = 0; ni < 5; ni++) acc[mi][ni] = (float4v){0.f, 0.f, 0.f, 0.f};
    short ov = (lr == 0) ? (short)0x3F80 : (short)0;
    short8 ones = {ov, ov, ov, ov, ov, ov, ov, ov};

    for (int st = 0; st < 8; st++) {
        // loads for buf[cur] were issued one full compute-phase ago -> drain is ~free
        asm volatile("s_waitcnt vmcnt(0)" ::: "memory");
        __builtin_amdgcn_s_barrier();       // all waves' loads landed; prev reads of buf^1 done
        asm volatile("" ::: "memory");
        const int cur = st & 1;
        if (st < 7) stageKV(cur ^ 1, nchunk + (st + 1) * 64);

        // phase A: rows n (mi 0..3), cols f' (wave w: 32 f, ni 0..1)
        float4v a2[4][2];
#pragma unroll
        for (int mi = 0; mi < 4; mi++)
#pragma unroll
            for (int ni = 0; ni < 2; ni++) a2[mi][ni] = (float4v){0.f, 0.f, 0.f, 0.f};
#pragma unroll
        for (int ks = 0; ks < 2; ks++) {
            short8 ka[4], pb[2];
#pragma unroll
            for (int mi = 0; mi < 4; mi++)
                ka[mi] = *(const short8*)&KB[cur][((mi * 2 + ks) * 64 + l) * 8];
#pragma unroll
            for (int ni = 0; ni < 2; ni++)
                pb[ni] = *(const short8*)&PB[(((w * 2 + ni) * 2 + ks) * 64 + l) * 8];
#pragma unroll
            for (int mi = 0; mi < 4; mi++)
#pragma unroll
                for (int ni = 0; ni < 2; ni++)
                    a2[mi][ni] = __builtin_amdgcn_mfma_f32_16x16x32_bf16(ka[mi], pb[ni], a2[mi][ni], 0, 0, 0);
        }
        // exp -> bf16 -> KPA (A-frag order, wave-local rows)
#pragma unroll
        for (int mi = 0; mi < 4; mi++) {
            int nb = mi * 16 + lq * 4;
            int qoff = ((nb >> 3) & 3) * 256 + (nb & 7) * 2;
            int setn = nb >> 5;
#pragma unroll
            for (int ni = 0; ni < 2; ni++) {
                int fp = w * 32 + ni * 16 + lr;
                float e0 = __expf(a2[mi][ni][0]);
                float e1 = __expf(a2[mi][ni][1]);
                float e2 = __expf(a2[mi][ni][2]);
                float e3 = __expf(a2[mi][ni][3]);
                uint2 p; p.x = pack2bf(e0, e1); p.y = pack2bf(e2, e3);
                *(uint2*)((char*)KPA + (size_t)(((fp >> 4) * 2 + setn) * 1024 + qoff + (fp & 15) * 16)) = p;
            }
        }
        // phase B: rows f' (wave w: mi 0..1), cols dh_ext (ni; ni=4 -> ksum)
#pragma unroll
        for (int ks = 0; ks < 2; ks++) {
            short8 af[2], bf[4];
#pragma unroll
            for (int mi = 0; mi < 2; mi++)
                af[mi] = *(const short8*)&KPA[(((w * 2 + mi) * 2 + ks) * 64 + l) * 8];
#pragma unroll
            for (int ni = 0; ni < 4; ni++)
                bf[ni] = *(const short8*)&VB[cur][((ni * 2 + ks) * 64 + l) * 8];
#pragma unroll
            for (int mi = 0; mi < 2; mi++) {
#pragma unroll
                for (int ni = 0; ni < 4; ni++)
                    acc[mi][ni] = __builtin_amdgcn_mfma_f32_16x16x32_bf16(af[mi], bf[ni], acc[mi][ni], 0, 0, 0);
                acc[mi][4] = __builtin_amdgcn_mfma_f32_16x16x32_bf16(af[mi], ones, acc[mi][4], 0, 0, 0);
            }
        }
    }
    unsigned short* base = partial + (size_t)(s * 16 + z) * 80 * 256 + fh * 128;
#pragma unroll
    for (int mi = 0; mi < 2; mi++) {
        int f0r = w * 32 + mi * 16 + lq * 4;
#pragma unroll
        for (int ni = 0; ni < 5; ni++) {
            int col = ni * 16 + lr;
#pragma unroll
            for (int r = 0; r < 4; r++)
                base[(size_t)col * 256 + f0r + r] = f2bf(acc[mi][ni][r]);
        }
    }
}

// ---------------------------------------------------------------------------
// Reduce split-K bf16 partials (16 splits) -> ctxT bf16 [z][80][256].
// ORIGINAL round-0 form restored: 160 blocks, ushort8v (16B) loads.
// (r4's 640-block dword-load version was a measured ~+11us regression — G13.)
// ---------------------------------------------------------------------------
__global__ __launch_bounds__(256) void ctx_reduce(const unsigned short* __restrict__ partial,
                                                  unsigned short* __restrict__ ctxT) {
    int idx8 = blockIdx.x * 256 + threadIdx.x;   // 0 .. 40959
    const int INNER = 16 * 80 * 256;
    size_t off = (size_t)idx8 * 8;
    float s0 = 0.f, s1 = 0.f, s2 = 0.f, s3 = 0.f, s4 = 0.f, s5 = 0.f, s6 = 0.f, s7 = 0.f;
#pragma unroll
    for (int k = 0; k < 16; k++) {
        ushort8v v = *(const ushort8v*)(partial + (size_t)k * INNER + off);
        s0 += bf2f(v[0]); s1 += bf2f(v[1]); s2 += bf2f(v[2]); s3 += bf2f(v[3]);
        s4 += bf2f(v[4]); s5 += bf2f(v[5]); s6 += bf2f(v[6]); s7 += bf2f(v[7]);
    }
    ushort8v o;
    o[0] = f2bf(s0); o[1] = f2bf(s1); o[2] = f2bf(s2); o[3] = f2bf(s3);
    o[4] = f2bf(s4); o[5] = f2bf(s5); o[6] = f2bf(s6); o[7] = f2bf(s7);
    *(ushort8v*)(ctxT + off) = o;
}

// ---------------------------------------------------------------------------
// Fused q' featuremap + (q'.ctx_ext). Round-5 dbuf form: PA/CB double-
// buffered, prefetch under compute, one barrier per fs-step. LDS 68 KB.
// ---------------------------------------------------------------------------
__global__ __launch_bounds__(256) void attn_fused_mfma(
    const unsigned short* __restrict__ qkvb,
    const unsigned short* __restrict__ projb,
    const unsigned short* __restrict__ ctxT,
    unsigned short* __restrict__ attnb)
{
    __shared__ __align__(16) unsigned short QB[16 * 512];      // 16 KB, resident
    __shared__ __align__(16) unsigned short PA[2][8 * 512];    // 16 KB dbuf
    __shared__ __align__(16) unsigned short QPA[16 * 512];     // 16 KB, wave-local
    __shared__ __align__(16) unsigned short CB[2][10 * 512];   // 20 KB dbuf
    const int t = threadIdx.x, w = t >> 6, l = t & 63;
    const int lr = l & 15, lq = l >> 4;
    const int m0 = blockIdx.x * 128, z = blockIdx.y;
    const int b = z >> 3, h = z & 7;

    auto stagePC = [&](int bi, int f0n) {
        for (int idx = w; idx < 8; idx += 4) {
            int fb = idx >> 1, kt = idx & 1;
            glds16(projb + (size_t)(f0n + fb * 16 + lr) * 64 + kt * 32 + lq * 8, &PA[bi][idx * 512]);
        }
        for (int idx = w; idx < 10; idx += 4) {
            int dhb = idx >> 1, ft = idx & 1;
            glds16(ctxT + ((size_t)z * 80 + dhb * 16 + lr) * 256 + f0n + ft * 32 + lq * 8,
                   &CB[bi][idx * 512]);
        }
    };

    // prologue: QB (4/thread) + step-0 PA/CB
    for (int idx = w; idx < 16; idx += 4) {
        int mblk = idx >> 1, kt = idx & 1;
        glds16(qkvb + ((size_t)b * NSEQ + m0 + mblk * 16 + lr) * QKV_ + h * 64 + kt * 32 + lq * 8,
               &QB[idx * 512]);
    }
    stagePC(0, 0);

    float4v acc[2][5];
#pragma unroll
    for (int mi = 0; mi < 2; mi++)
#pragma unroll
        for (int ni = 0; ni < 5; ni++) acc[mi][ni] = (float4v){0.f, 0.f, 0.f, 0.f};

    for (int fs = 0; fs < 4; fs++) {
        asm volatile("s_waitcnt vmcnt(0)" ::: "memory");
        __builtin_amdgcn_s_barrier();
        asm volatile("" ::: "memory");
        const int cur = fs & 1;
        if (fs < 3) stagePC(cur ^ 1, (fs + 1) * 64);

        float4v a2[4][2];
#pragma unroll
        for (int mi = 0; mi < 4; mi++)
#pragma unroll
            for (int ni = 0; ni < 2; ni++) a2[mi][ni] = (float4v){0.f, 0.f, 0.f, 0.f};
#pragma unroll
        for (int ks = 0; ks < 2; ks++) {
            short8 pa[4], qb[2];
#pragma unroll
            for (int mi = 0; mi < 4; mi++)
                pa[mi] = *(const short8*)&PA[cur][((mi * 2 + ks) * 64 + l) * 8];
#pragma unroll
            for (int ni = 0; ni < 2; ni++)
                qb[ni] = *(const short8*)&QB[(((w * 2 + ni) * 2 + ks) * 64 + l) * 8];
#pragma unroll
            for (int mi = 0; mi < 4; mi++)
#pragma unroll
                for (int ni = 0; ni < 2; ni++)
                    a2[mi][ni] = __builtin_amdgcn_mfma_f32_16x16x32_bf16(pa[mi], qb[ni], a2[mi][ni], 0, 0, 0);
        }
#pragma unroll
        for (int mi = 0; mi < 4; mi++) {
            int fb2 = mi * 16 + lq * 4;
            int qoff = ((fb2 >> 3) & 3) * 256 + (fb2 & 7) * 2;
            int setf = fb2 >> 5;
#pragma unroll
            for (int ni = 0; ni < 2; ni++) {
                int m = w * 32 + ni * 16 + lr;
                float e0 = __expf(0.125f * a2[mi][ni][0]);
                float e1 = __expf(0.125f * a2[mi][ni][1]);
                float e2 = __expf(0.125f * a2[mi][ni][2]);
                float e3 = __expf(0.125f * a2[mi][ni][3]);
                uint2 p; p.x = pack2bf(e0, e1); p.y = pack2bf(e2, e3);
                *(uint2*)((char*)QPA + (size_t)(((m >> 4) * 2 + setf) * 1024 + qoff + (m & 15) * 16)) = p;
            }
        }
#pragma unroll
        for (int ks = 0; ks < 2; ks++) {
            short8 af[2], cb[5];
#pragma unroll
            for (int mi = 0; mi < 2; mi++)
                af[mi] = *(const short8*)&QPA[(((w * 2 + mi) * 2 + ks) * 64 + l) * 8];
#pragma unroll
            for (int ni = 0; ni < 5; ni++)
                cb[ni] = *(const short8*)&CB[cur][((ni * 2 + ks) * 64 + l) * 8];
#pragma unroll
            for (int mi = 0; mi < 2; mi++)
#pragma unroll
                for (int ni = 0; ni < 5; ni++)
                    acc[mi][ni] = __builtin_amdgcn_mfma_f32_16x16x32_bf16(af[mi], cb[ni], acc[mi][ni], 0, 0, 0);
        }
    }
#pragma unroll
    for (int mi = 0; mi < 2; mi++) {
        int rowb = m0 + w * 32 + mi * 16 + lq * 4;
#pragma unroll
        for (int r = 0; r < 4; r++) {
            float dv = __shfl(acc[mi][4][r], (l & 48), 64);
            float rinv = 1.f / (dv + 1e-6f);
#pragma unroll
            for (int ni = 0; ni < 4; ni++)
                attnb[((size_t)b * NSEQ + rowb + r) * 512 + h * 64 + ni * 16 + lr] =
                    f2bf(acc[mi][ni][r] * rinv);
        }
    }
}

// ---------------------------------------------------------------------------
extern "C" void kernel_launch(void* const* d_in, const int* in_sizes, int n_in,
                              void* d_out, int out_size, void* d_ws, size_t ws_size,
                              hipStream_t stream) {
    const float* x    = (const float*)d_in[0];
    const float* Wqkv = (const float*)d_in[1];
    const float* Wout = (const float*)d_in[2];
    const float* bout = (const float*)d_in[3];
    const float* proj = (const float*)d_in[4];

    unsigned short* qkvb    = (unsigned short*)d_ws;                 // 25,165,824 u16
    unsigned short* vT      = qkvb + (size_t)M_ * QKV_;              // 8,388,608 u16
    unsigned short* partial = vT + (size_t)16 * 64 * NSEQ;           // 5,242,880 u16 (bf16, 16 splits)
    unsigned short* ctxT    = partial + (size_t)16 * 16 * 80 * 256;  // 327,680 u16
    unsigned short* projb   = ctxT + (size_t)16 * 80 * 256;          // 16,384 u16
    unsigned short* xb      = projb + 16384;                         // 8,388,608 u16
    unsigned short* attnb   = xb;                                    // overlay (xb dead after gemm1)
    unsigned short* wqkvb   = xb + (size_t)M_ * DIM_;                // 786,432 u16
    unsigned short* woutb   = wqkvb + (size_t)QKV_ * DIM_;           // 262,144 u16
    float* outp = (float*)d_out;                                     // total ws ~97 MB

    // 0) fp32 -> bf16 (single launch)
    cvt_all<<<dim3(4616), 256, 0, stream>>>(x, Wqkv, Wout, proj, xb, wqkvb, woutb, projb);
    // 1) qkv = x @ Wqkv^T — best-measured gemm1; grid (12, 128) = 1536 blocks
    gemm_nt_pp<true><<<dim3(QKV_ / 128, M_ / 128), 256, 0, stream>>>(xb, wqkvb, nullptr, qkvb, vT, M_, QKV_, DIM_);
    // 2) fused k' + context partials — dbuf prefetch, 1 barrier/step
    ctx_fused_mfma<<<dim3(16, 2, 16), 256, 0, stream>>>(qkvb, projb, vT, partial);
    // 3) reduce -> ctxT bf16 — ORIGINAL 160-block 16B-load form
    ctx_reduce<<<dim3(160), 256, 0, stream>>>(partial, ctxT);
    // 4) fused q' + attention out — dbuf prefetch, 1 barrier/step
    attn_fused_mfma<<<dim3(64, 16), 256, 0, stream>>>(qkvb, projb, ctxT, attnb);
    // 5) out = attn @ Wout^T + bout — grid (4, 64) = 256 blocks
    gemm_out_256<<<dim3(DIM_ / 128, M_ / 256), 512, 0, stream>>>(attnb, woutb, bout, outp, M_, DIM_, DIM_);
}

// Round 7
// 209.741 us; speedup vs baseline: 1.0337x; 1.0020x over previous
//
#include <hip/hip_runtime.h>
#include <math.h>

#define B_    2
#define NSEQ  8192
#define DIM_  512
#define H_    8
#define DH_   64
#define F_    256
#define M_    (B_*NSEQ)      // 16384
#define QKV_  1536

typedef __attribute__((ext_vector_type(8))) short     short8;
typedef __attribute__((ext_vector_type(4))) float     float4v;
typedef __attribute__((ext_vector_type(8))) unsigned short ushort8v;

__device__ __forceinline__ unsigned short f2bf(float f) {
    unsigned u = __float_as_uint(f);
    u += 0x7FFFu + ((u >> 16) & 1u);   // RNE
    return (unsigned short)(u >> 16);
}
__device__ __forceinline__ float bf2f(unsigned short h) {
    unsigned u = ((unsigned)h) << 16;
    return __uint_as_float(u);
}
// pack two floats -> two bf16 (truncate; bias cancels in N/D ratio)
__device__ __forceinline__ unsigned pack2bf(float lo, float hi) {
    return __builtin_amdgcn_perm(__float_as_uint(hi), __float_as_uint(lo), 0x07060302);
}
__device__ __forceinline__ void glds16(const void* g, void* s) {
    __builtin_amdgcn_global_load_lds(
        (const __attribute__((address_space(1))) unsigned int*)g,
        (__attribute__((address_space(3))) unsigned int*)s, 16, 0, 0);
}

// ---------------------------------------------------------------------------
// fused fp32->bf16 for all 4 inputs, one launch.
// ---------------------------------------------------------------------------
__global__ __launch_bounds__(256) void cvt_all(const float* __restrict__ x,
                                               const float* __restrict__ wqkv,
                                               const float* __restrict__ wout,
                                               const float* __restrict__ proj,
                                               unsigned short* __restrict__ xb,
                                               unsigned short* __restrict__ wqkvb,
                                               unsigned short* __restrict__ woutb,
                                               unsigned short* __restrict__ projb) {
    int bid = blockIdx.x;
    const float* in; unsigned short* out; int i;
    if (bid < 4096)      { in = x;    out = xb;    i = bid * 256 + threadIdx.x; }
    else if (bid < 4480) { in = wqkv; out = wqkvb; i = (bid - 4096) * 256 + threadIdx.x; }
    else if (bid < 4608) { in = wout; out = woutb; i = (bid - 4480) * 256 + threadIdx.x; }
    else                 { in = proj; out = projb; i = (bid - 4608) * 256 + threadIdx.x; }
    float4 a = ((const float4*)in)[2 * i];
    float4 b = ((const float4*)in)[2 * i + 1];
    ushort8v o;
    o[0] = f2bf(a.x); o[1] = f2bf(a.y); o[2] = f2bf(a.z); o[3] = f2bf(a.w);
    o[4] = f2bf(b.x); o[5] = f2bf(b.y); o[6] = f2bf(b.z); o[7] = f2bf(b.w);
    ((ushort8v*)out)[i] = o;
}

// ---------------------------------------------------------------------------
// gemm1: OCCUPANCY EXPERIMENT. Same 128x128 tile, same verified 3-ring /
// counted-vmcnt schedule / LDS layout as the 63.5us kernel — but 8 waves
// (512 thr), per-wave tile 64x32 (wm 0..1 x wn 0..3): acc = 32 AGPR (was 64),
// launch_bounds(512,6) caps unified regs at ~85 -> target 6 waves/SIMD =
// 24 waves/CU (2x the VGPR+AGPR-capped 12 of the 4-wave version).
// Theory: gemm1 time has tracked ONLY resident waves across r0-r6.
// Staging: waves 0-3 stage A chunks, 4-7 stage B; 2 glds/thread/tile ->
// vmcnt(2) ladder (ring-3, prefetch depth 2, identical discipline).
// vTout: V-columns (col>=1024) written transposed into vT.
// ---------------------------------------------------------------------------
template<bool BF16OUT>
__global__ __launch_bounds__(512, 6) void gemm_nt_pp(const unsigned short* __restrict__ A,
                                                     const unsigned short* __restrict__ Bm,
                                                     const float* __restrict__ bias,
                                                     void* __restrict__ Cout,
                                                     unsigned short* __restrict__ vTout,
                                                     int M, int N, int K) {
    __shared__ __align__(16) unsigned short As[3][128 * 32];   // 24 KB
    __shared__ __align__(16) unsigned short Bs[3][128 * 32];   // 24 KB
    const int t  = threadIdx.x;
    const int w  = t >> 6, l = t & 63;
    const int wm = w >> 2, wn = w & 3;          // 2 M x 4 N wave grid
    const int lr = l & 15, lq = l >> 4;

    // XCD-aware remap: contiguous tile range per XCD (flat % 8 = XCD)
    const int gx = gridDim.x;
    int flat = blockIdx.y * gx + blockIdx.x;
    int per  = (gx * gridDim.y) >> 3;
    int flat2 = (flat & 7) * per + (flat >> 3);
    const int m0 = (flat2 / gx) * 128, n0 = (flat2 % gx) * 128;

    float4v acc[4][2];                          // 64x32 per wave: mi 4 x ni 2
#pragma unroll
    for (int mi = 0; mi < 4; mi++)
#pragma unroll
        for (int ni = 0; ni < 2; ni++) acc[mi][ni] = (float4v){0.f, 0.f, 0.f, 0.f};

    // one BK=32 tile = 16 chunks (8 A + 8 B); 8 waves x 2 glds = 2/thread
    auto stage = [&](int buf, int k0) {
        if (w < 4) {
#pragma unroll
            for (int i = 0; i < 2; i++) {
                int c = w * 2 + i;
                glds16(A + (size_t)(m0 + c * 16 + lr) * K + k0 + lq * 8, &As[buf][c * 512]);
            }
        } else {
#pragma unroll
            for (int i = 0; i < 2; i++) {
                int c = (w - 4) * 2 + i;
                glds16(Bm + (size_t)(n0 + c * 16 + lr) * K + k0 + lq * 8, &Bs[buf][c * 512]);
            }
        }
    };

    const int nk = K >> 5;          // 16 for K=512
    stage(0, 0);
    stage(1, 32);

    for (int k = 0; k < nk; k++) {
        // counted wait: tile k landed; tile k+1's 2 loads stay in flight
        if (k + 1 < nk) { asm volatile("s_waitcnt vmcnt(2)" ::: "memory"); }
        else            { asm volatile("s_waitcnt vmcnt(0)" ::: "memory"); }
        __builtin_amdgcn_s_barrier();

        const int cur = k % 3;
        if (k + 2 < nk) stage((k + 2) % 3, (k + 2) << 5);

        short8 af[4], bfr[2];
#pragma unroll
        for (int mi = 0; mi < 4; mi++)
            af[mi] = *(const short8*)&As[cur][((wm * 4 + mi) * 64 + l) * 8];
#pragma unroll
        for (int ni = 0; ni < 2; ni++)
            bfr[ni] = *(const short8*)&Bs[cur][((wn * 2 + ni) * 64 + l) * 8];

        __builtin_amdgcn_s_setprio(1);
#pragma unroll
        for (int mi = 0; mi < 4; mi++)
#pragma unroll
            for (int ni = 0; ni < 2; ni++)
                acc[mi][ni] = __builtin_amdgcn_mfma_f32_16x16x32_bf16(
                    af[mi], bfr[ni], acc[mi][ni], 0, 0, 0);
        __builtin_amdgcn_s_setprio(0);
    }

    const int q = l >> 4, c = l & 15;      // C/D: col=lane&15, row=quad*4+reg
#pragma unroll
    for (int mi = 0; mi < 4; mi++) {
        int row0 = m0 + wm * 64 + mi * 16 + q * 4;
#pragma unroll
        for (int ni = 0; ni < 2; ni++) {
            int col = n0 + wn * 32 + ni * 16 + c;
            if (BF16OUT && vTout != nullptr && col >= 1024) {
                // V path: write transposed into vT[z=b*8+h][dh][seq]
                int cm = col - 1024;
                int h2 = cm >> 6, dh = cm & 63;
                int bq = row0 >> 13;
                size_t nn = (size_t)(row0 & 8191);
                unsigned short* dst = vTout + (((size_t)bq * 8 + h2) * 64 + dh) * NSEQ + nn;
                uint2 pv;
                pv.x = ((unsigned)f2bf(acc[mi][ni][1]) << 16) | f2bf(acc[mi][ni][0]);
                pv.y = ((unsigned)f2bf(acc[mi][ni][3]) << 16) | f2bf(acc[mi][ni][2]);
                *(uint2*)dst = pv;
            } else {
                float bv = bias ? bias[col] : 0.f;
#pragma unroll
                for (int r = 0; r < 4; r++) {
                    float v = acc[mi][ni][r] + bv;
                    if (BF16OUT) ((unsigned short*)Cout)[(size_t)(row0 + r) * N + col] = f2bf(v);
                    else         ((float*)Cout)[(size_t)(row0 + r) * N + col] = v;
                }
            }
        }
    }
}

// ---------------------------------------------------------------------------
// gemm2: round-1/4 form. BM=256, BN=128, BK=64, 512 threads, 3-ring, vmcnt(6).
// fp32 out + bias. K hardcoded 512 (nk=8). FROZEN.
// ---------------------------------------------------------------------------
__global__ __launch_bounds__(512) void gemm_out_256(const unsigned short* __restrict__ A,
                                                    const unsigned short* __restrict__ Bm,
                                                    const float* __restrict__ bias,
                                                    float* __restrict__ Cout,
                                                    int M, int N, int K) {
    __shared__ __align__(16) unsigned short As[3][32 * 512];   // 96 KB
    __shared__ __align__(16) unsigned short Bs[3][16 * 512];   // 48 KB
    const int t  = threadIdx.x;
    const int w  = t >> 6, l = t & 63;
    const int wm = w >> 1, wn = w & 1;
    const int lr = l & 15, lq = l >> 4;

    const int gx = gridDim.x;
    int flat = blockIdx.y * gx + blockIdx.x;
    int per  = (gx * gridDim.y) >> 3;
    int flat2 = (flat & 7) * per + (flat >> 3);
    const int m0 = (flat2 / gx) * 256, n0 = (flat2 % gx) * 128;

    float4v acc[4][4];
#pragma unroll
    for (int mi = 0; mi < 4; mi++)
#pragma unroll
        for (int ni = 0; ni < 4; ni++) acc[mi][ni] = (float4v){0.f, 0.f, 0.f, 0.f};

    auto stage = [&](int buf, int k0) {
#pragma unroll
        for (int i = 0; i < 4; i++) {
            int c = w * 4 + i, rb = c >> 1, ks = c & 1;
            glds16(A + (size_t)(m0 + rb * 16 + lr) * K + k0 + ks * 32 + lq * 8,
                   &As[buf][c * 512]);
        }
#pragma unroll
        for (int i = 0; i < 2; i++) {
            int c = w * 2 + i, rb = c >> 1, ks = c & 1;
            glds16(Bm + (size_t)(n0 + rb * 16 + lr) * K + k0 + ks * 32 + lq * 8,
                   &Bs[buf][c * 512]);
        }
    };

    stage(0, 0);
    stage(1, 64);

#pragma unroll
    for (int k = 0; k < 8; k++) {
        if (k < 7) { asm volatile("s_waitcnt vmcnt(6)" ::: "memory"); }
        else       { asm volatile("s_waitcnt vmcnt(0)" ::: "memory"); }
        __builtin_amdgcn_s_barrier();
        const int cur = k % 3;

        if (k + 2 < 8) stage((k + 2) % 3, (k + 2) << 6);

        short8 af[2][4], bfr[2][4];
#pragma unroll
        for (int ks = 0; ks < 2; ks++) {
#pragma unroll
            for (int mi = 0; mi < 4; mi++)
                af[ks][mi] = *(const short8*)&As[cur][(((wm * 4 + mi) * 2 + ks) * 64 + l) * 8];
#pragma unroll
            for (int ni = 0; ni < 4; ni++)
                bfr[ks][ni] = *(const short8*)&Bs[cur][(((wn * 4 + ni) * 2 + ks) * 64 + l) * 8];
        }

        __builtin_amdgcn_s_setprio(1);
#pragma unroll
        for (int ks = 0; ks < 2; ks++)
#pragma unroll
            for (int mi = 0; mi < 4; mi++)
#pragma unroll
                for (int ni = 0; ni < 4; ni++)
                    acc[mi][ni] = __builtin_amdgcn_mfma_f32_16x16x32_bf16(
                        af[ks][mi], bfr[ks][ni], acc[mi][ni], 0, 0, 0);
        __builtin_amdgcn_s_setprio(0);
    }

    const int q = l >> 4, c = l & 15;
#pragma unroll
    for (int mi = 0; mi < 4; mi++) {
        int row0 = m0 + wm * 64 + mi * 16 + q * 4;
#pragma unroll
        for (int ni = 0; ni < 4; ni++) {
            int col = n0 + wn * 64 + ni * 16 + c;
            float bv = bias ? bias[col] : 0.f;
#pragma unroll
            for (int r = 0; r < 4; r++)
                Cout[(size_t)(row0 + r) * N + col] = acc[mi][ni][r] + bv;
        }
    }
}

// ---------------------------------------------------------------------------
// Fused k' featuremap + split-K context. Round-5 dbuf form. FROZEN.
// ---------------------------------------------------------------------------
__global__ __launch_bounds__(256) void ctx_fused_mfma(
    const unsigned short* __restrict__ qkvb,
    const unsigned short* __restrict__ projb,
    const unsigned short* __restrict__ vT,
    unsigned short* __restrict__ partial)   // [16 s][16 z][80][256] bf16
{
    __shared__ __align__(16) unsigned short PB[16 * 512];      // 16 KB, resident
    __shared__ __align__(16) unsigned short KB[2][8 * 512];    // 16 KB dbuf
    __shared__ __align__(16) unsigned short VB[2][8 * 512];    // 16 KB dbuf
    __shared__ __align__(16) unsigned short KPA[16 * 512];     // 16 KB, wave-local
    const int t = threadIdx.x, w = t >> 6, l = t & 63;
    const int lr = l & 15, lq = l >> 4;
    const int s = blockIdx.x, fh = blockIdx.y, z = blockIdx.z;
    const int b = z >> 3, h = z & 7;
    const int nchunk = s * 512;

    auto stageKV = [&](int bi, int nbase) {
        for (int idx = w; idx < 8; idx += 4) {
            int nblk = idx >> 1, kt = idx & 1;
            glds16(qkvb + ((size_t)b * NSEQ + nbase + nblk * 16 + lr) * QKV_ + 512 + h * 64 + kt * 32 + lq * 8,
                   &KB[bi][idx * 512]);
        }
        for (int idx = w; idx < 8; idx += 4) {
            int dhb = idx >> 1, nt2 = idx & 1;
            glds16(vT + ((size_t)z * 64 + dhb * 16 + lr) * NSEQ + nbase + nt2 * 32 + lq * 8,
                   &VB[bi][idx * 512]);
        }
    };

    // prologue: PB (4 glds/thread) + step-0 K/V (4 glds/thread)
    for (int idx = w; idx < 16; idx += 4) {
        int fblk = idx >> 1, kt = idx & 1;
        glds16(projb + (size_t)(fh * 128 + fblk * 16 + lr) * 64 + kt * 32 + lq * 8, &PB[idx * 512]);
    }
    stageKV(0, nchunk);

    float4v acc[2][5];
#pragma unroll
    for (int mi = 0; mi < 2; mi++)
#pragma unroll
        for (int ni = 0; ni < 5; ni++) acc[mi][ni] = (float4v){0.f, 0.f, 0.f, 0.f};
    short ov = (lr == 0) ? (short)0x3F80 : (short)0;
    short8 ones = {ov, ov, ov, ov, ov, ov, ov, ov};

    for (int st = 0; st < 8; st++) {
        asm volatile("s_waitcnt vmcnt(0)" ::: "memory");
        __builtin_amdgcn_s_barrier();
        asm volatile("" ::: "memory");
        const int cur = st & 1;
        if (st < 7) stageKV(cur ^ 1, nchunk + (st + 1) * 64);

        // phase A: rows n (mi 0..3), cols f' (wave w: 32 f, ni 0..1)
        float4v a2[4][2];
#pragma unroll
        for (int mi = 0; mi < 4; mi++)
#pragma unroll
            for (int ni = 0; ni < 2; ni++) a2[mi][ni] = (float4v){0.f, 0.f, 0.f, 0.f};
#pragma unroll
        for (int ks = 0; ks < 2; ks++) {
            short8 ka[4], pb[2];
#pragma unroll
            for (int mi = 0; mi < 4; mi++)
                ka[mi] = *(const short8*)&KB[cur][((mi * 2 + ks) * 64 + l) * 8];
#pragma unroll
            for (int ni = 0; ni < 2; ni++)
                pb[ni] = *(const short8*)&PB[(((w * 2 + ni) * 2 + ks) * 64 + l) * 8];
#pragma unroll
            for (int mi = 0; mi < 4; mi++)
#pragma unroll
                for (int ni = 0; ni < 2; ni++)
                    a2[mi][ni] = __builtin_amdgcn_mfma_f32_16x16x32_bf16(ka[mi], pb[ni], a2[mi][ni], 0, 0, 0);
        }
        // exp -> bf16 -> KPA (A-frag order, wave-local rows)
#pragma unroll
        for (int mi = 0; mi < 4; mi++) {
            int nb = mi * 16 + lq * 4;
            int qoff = ((nb >> 3) & 3) * 256 + (nb & 7) * 2;
            int setn = nb >> 5;
#pragma unroll
            for (int ni = 0; ni < 2; ni++) {
                int fp = w * 32 + ni * 16 + lr;
                float e0 = __expf(a2[mi][ni][0]);
                float e1 = __expf(a2[mi][ni][1]);
                float e2 = __expf(a2[mi][ni][2]);
                float e3 = __expf(a2[mi][ni][3]);
                uint2 p; p.x = pack2bf(e0, e1); p.y = pack2bf(e2, e3);
                *(uint2*)((char*)KPA + (size_t)(((fp >> 4) * 2 + setn) * 1024 + qoff + (fp & 15) * 16)) = p;
            }
        }
        // phase B: rows f' (wave w: mi 0..1), cols dh_ext (ni; ni=4 -> ksum)
#pragma unroll
        for (int ks = 0; ks < 2; ks++) {
            short8 af[2], bf[4];
#pragma unroll
            for (int mi = 0; mi < 2; mi++)
                af[mi] = *(const short8*)&KPA[(((w * 2 + mi) * 2 + ks) * 64 + l) * 8];
#pragma unroll
            for (int ni = 0; ni < 4; ni++)
                bf[ni] = *(const short8*)&VB[cur][((ni * 2 + ks) * 64 + l) * 8];
#pragma unroll
            for (int mi = 0; mi < 2; mi++) {
#pragma unroll
                for (int ni = 0; ni < 4; ni++)
                    acc[mi][ni] = __builtin_amdgcn_mfma_f32_16x16x32_bf16(af[mi], bf[ni], acc[mi][ni], 0, 0, 0);
                acc[mi][4] = __builtin_amdgcn_mfma_f32_16x16x32_bf16(af[mi], ones, acc[mi][4], 0, 0, 0);
            }
        }
    }
    unsigned short* base = partial + (size_t)(s * 16 + z) * 80 * 256 + fh * 128;
#pragma unroll
    for (int mi = 0; mi < 2; mi++) {
        int f0r = w * 32 + mi * 16 + lq * 4;
#pragma unroll
        for (int ni = 0; ni < 5; ni++) {
            int col = ni * 16 + lr;
#pragma unroll
            for (int r = 0; r < 4; r++)
                base[(size_t)col * 256 + f0r + r] = f2bf(acc[mi][ni][r]);
        }
    }
}

// ---------------------------------------------------------------------------
// Reduce split-K bf16 partials (16 splits) -> ctxT bf16 [z][80][256].
// 160 blocks, ushort8v (16B) loads. FROZEN.
// ---------------------------------------------------------------------------
__global__ __launch_bounds__(256) void ctx_reduce(const unsigned short* __restrict__ partial,
                                                  unsigned short* __restrict__ ctxT) {
    int idx8 = blockIdx.x * 256 + threadIdx.x;   // 0 .. 40959
    const int INNER = 16 * 80 * 256;
    size_t off = (size_t)idx8 * 8;
    float s0 = 0.f, s1 = 0.f, s2 = 0.f, s3 = 0.f, s4 = 0.f, s5 = 0.f, s6 = 0.f, s7 = 0.f;
#pragma unroll
    for (int k = 0; k < 16; k++) {
        ushort8v v = *(const ushort8v*)(partial + (size_t)k * INNER + off);
        s0 += bf2f(v[0]); s1 += bf2f(v[1]); s2 += bf2f(v[2]); s3 += bf2f(v[3]);
        s4 += bf2f(v[4]); s5 += bf2f(v[5]); s6 += bf2f(v[6]); s7 += bf2f(v[7]);
    }
    ushort8v o;
    o[0] = f2bf(s0); o[1] = f2bf(s1); o[2] = f2bf(s2); o[3] = f2bf(s3);
    o[4] = f2bf(s4); o[5] = f2bf(s5); o[6] = f2bf(s6); o[7] = f2bf(s7);
    *(ushort8v*)(ctxT + off) = o;
}

// ---------------------------------------------------------------------------
// Fused q' featuremap + (q'.ctx_ext). Round-5 dbuf form. FROZEN.
// ---------------------------------------------------------------------------
__global__ __launch_bounds__(256) void attn_fused_mfma(
    const unsigned short* __restrict__ qkvb,
    const unsigned short* __restrict__ projb,
    const unsigned short* __restrict__ ctxT,
    unsigned short* __restrict__ attnb)
{
    __shared__ __align__(16) unsigned short QB[16 * 512];      // 16 KB, resident
    __shared__ __align__(16) unsigned short PA[2][8 * 512];    // 16 KB dbuf
    __shared__ __align__(16) unsigned short QPA[16 * 512];     // 16 KB, wave-local
    __shared__ __align__(16) unsigned short CB[2][10 * 512];   // 20 KB dbuf
    const int t = threadIdx.x, w = t >> 6, l = t & 63;
    const int lr = l & 15, lq = l >> 4;
    const int m0 = blockIdx.x * 128, z = blockIdx.y;
    const int b = z >> 3, h = z & 7;

    auto stagePC = [&](int bi, int f0n) {
        for (int idx = w; idx < 8; idx += 4) {
            int fb = idx >> 1, kt = idx & 1;
            glds16(projb + (size_t)(f0n + fb * 16 + lr) * 64 + kt * 32 + lq * 8, &PA[bi][idx * 512]);
        }
        for (int idx = w; idx < 10; idx += 4) {
            int dhb = idx >> 1, ft = idx & 1;
            glds16(ctxT + ((size_t)z * 80 + dhb * 16 + lr) * 256 + f0n + ft * 32 + lq * 8,
                   &CB[bi][idx * 512]);
        }
    };

    // prologue: QB (4/thread) + step-0 PA/CB
    for (int idx = w; idx < 16; idx += 4) {
        int mblk = idx >> 1, kt = idx & 1;
        glds16(qkvb + ((size_t)b * NSEQ + m0 + mblk * 16 + lr) * QKV_ + h * 64 + kt * 32 + lq * 8,
               &QB[idx * 512]);
    }
    stagePC(0, 0);

    float4v acc[2][5];
#pragma unroll
    for (int mi = 0; mi < 2; mi++)
#pragma unroll
        for (int ni = 0; ni < 5; ni++) acc[mi][ni] = (float4v){0.f, 0.f, 0.f, 0.f};

    for (int fs = 0; fs < 4; fs++) {
        asm volatile("s_waitcnt vmcnt(0)" ::: "memory");
        __builtin_amdgcn_s_barrier();
        asm volatile("" ::: "memory");
        const int cur = fs & 1;
        if (fs < 3) stagePC(cur ^ 1, (fs + 1) * 64);

        float4v a2[4][2];
#pragma unroll
        for (int mi = 0; mi < 4; mi++)
#pragma unroll
            for (int ni = 0; ni < 2; ni++) a2[mi][ni] = (float4v){0.f, 0.f, 0.f, 0.f};
#pragma unroll
        for (int ks = 0; ks < 2; ks++) {
            short8 pa[4], qb[2];
#pragma unroll
            for (int mi = 0; mi < 4; mi++)
                pa[mi] = *(const short8*)&PA[cur][((mi * 2 + ks) * 64 + l) * 8];
#pragma unroll
            for (int ni = 0; ni < 2; ni++)
                qb[ni] = *(const short8*)&QB[(((w * 2 + ni) * 2 + ks) * 64 + l) * 8];
#pragma unroll
            for (int mi = 0; mi < 4; mi++)
#pragma unroll
                for (int ni = 0; ni < 2; ni++)
                    a2[mi][ni] = __builtin_amdgcn_mfma_f32_16x16x32_bf16(pa[mi], qb[ni], a2[mi][ni], 0, 0, 0);
        }
#pragma unroll
        for (int mi = 0; mi < 4; mi++) {
            int fb2 = mi * 16 + lq * 4;
            int qoff = ((fb2 >> 3) & 3) * 256 + (fb2 & 7) * 2;
            int setf = fb2 >> 5;
#pragma unroll
            for (int ni = 0; ni < 2; ni++) {
                int m = w * 32 + ni * 16 + lr;
                float e0 = __expf(0.125f * a2[mi][ni][0]);
                float e1 = __expf(0.125f * a2[mi][ni][1]);
                float e2 = __expf(0.125f * a2[mi][ni][2]);
                float e3 = __expf(0.125f * a2[mi][ni][3]);
                uint2 p; p.x = pack2bf(e0, e1); p.y = pack2bf(e2, e3);
                *(uint2*)((char*)QPA + (size_t)(((m >> 4) * 2 + setf) * 1024 + qoff + (m & 15) * 16)) = p;
            }
        }
#pragma unroll
        for (int ks = 0; ks < 2; ks++) {
            short8 af[2], cb[5];
#pragma unroll
            for (int mi = 0; mi < 2; mi++)
                af[mi] = *(const short8*)&QPA[(((w * 2 + mi) * 2 + ks) * 64 + l) * 8];
#pragma unroll
            for (int ni = 0; ni < 5; ni++)
                cb[ni] = *(const short8*)&CB[cur][((ni * 2 + ks) * 64 + l) * 8];
#pragma unroll
            for (int mi = 0; mi < 2; mi++)
#pragma unroll
                for (int ni = 0; ni < 5; ni++)
                    acc[mi][ni] = __builtin_amdgcn_mfma_f32_16x16x32_bf16(af[mi], cb[ni], acc[mi][ni], 0, 0, 0);
        }
    }
#pragma unroll
    for (int mi = 0; mi < 2; mi++) {
        int rowb = m0 + w * 32 + mi * 16 + lq * 4;
#pragma unroll
        for (int r = 0; r < 4; r++) {
            float dv = __shfl(acc[mi][4][r], (l & 48), 64);
            float rinv = 1.f / (dv + 1e-6f);
#pragma unroll
            for (int ni = 0; ni < 4; ni++)
                attnb[((size_t)b * NSEQ + rowb + r) * 512 + h * 64 + ni * 16 + lr] =
                    f2bf(acc[mi][ni][r] * rinv);
        }
    }
}

// ---------------------------------------------------------------------------
extern "C" void kernel_launch(void* const* d_in, const int* in_sizes, int n_in,
                              void* d_out, int out_size, void* d_ws, size_t ws_size,
                              hipStream_t stream) {
    const float* x    = (const float*)d_in[0];
    const float* Wqkv = (const float*)d_in[1];
    const float* Wout = (const float*)d_in[2];
    const float* bout = (const float*)d_in[3];
    const float* proj = (const float*)d_in[4];

    unsigned short* qkvb    = (unsigned short*)d_ws;                 // 25,165,824 u16
    unsigned short* vT      = qkvb + (size_t)M_ * QKV_;              // 8,388,608 u16
    unsigned short* partial = vT + (size_t)16 * 64 * NSEQ;           // 5,242,880 u16 (bf16, 16 splits)
    unsigned short* ctxT    = partial + (size_t)16 * 16 * 80 * 256;  // 327,680 u16
    unsigned short* projb   = ctxT + (size_t)16 * 80 * 256;          // 16,384 u16
    unsigned short* xb      = projb + 16384;                         // 8,388,608 u16
    unsigned short* attnb   = xb;                                    // overlay (xb dead after gemm1)
    unsigned short* wqkvb   = xb + (size_t)M_ * DIM_;                // 786,432 u16
    unsigned short* woutb   = wqkvb + (size_t)QKV_ * DIM_;           // 262,144 u16
    float* outp = (float*)d_out;                                     // total ws ~97 MB

    // 0) fp32 -> bf16 (single launch)
    cvt_all<<<dim3(4616), 256, 0, stream>>>(x, Wqkv, Wout, proj, xb, wqkvb, woutb, projb);
    // 1) qkv = x @ Wqkv^T — 8-wave occupancy experiment; grid (12, 128), 512 thr
    gemm_nt_pp<true><<<dim3(QKV_ / 128, M_ / 128), 512, 0, stream>>>(xb, wqkvb, nullptr, qkvb, vT, M_, QKV_, DIM_);
    // 2) fused k' + context partials — dbuf prefetch, 1 barrier/step
    ctx_fused_mfma<<<dim3(16, 2, 16), 256, 0, stream>>>(qkvb, projb, vT, partial);
    // 3) reduce -> ctxT bf16 — 160-block 16B-load form
    ctx_reduce<<<dim3(160), 256, 0, stream>>>(partial, ctxT);
    // 4) fused q' + attention out — dbuf prefetch, 1 barrier/step
    attn_fused_mfma<<<dim3(64, 16), 256, 0, stream>>>(qkvb, projb, ctxT, attnb);
    // 5) out = attn @ Wout^T + bout — grid (4, 64) = 256 blocks
    gemm_out_256<<<dim3(DIM_ / 128, M_ / 256), 512, 0, stream>>>(attnb, woutb, bout, outp, M_, DIM_, DIM_);
}